// Round 11
// baseline (414.679 us; speedup 1.0000x reference)
//
#include <hip/hip_runtime.h>
#include <hip/hip_bf16.h>

#define N_DIM 8192
#define E_DIM 2048
#define NKT 32           // K tiles of BK=64

typedef __bf16 bf16x8 __attribute__((ext_vector_type(8)));
typedef float  f32x4  __attribute__((ext_vector_type(4)));
typedef short  short8 __attribute__((ext_vector_type(8)));

#define GLD(gp, lp) __builtin_amdgcn_global_load_lds( \
    (const __attribute__((address_space(1))) void*)(gp), \
    (__attribute__((address_space(3))) void*)(lp), 16, 0, 0)

// ---------------- conversion: A fp32 [N,E] -> bf16 [N,E] ----------------
__global__ __launch_bounds__(256) void cvtA(const float* __restrict__ A,
                                            __hip_bfloat16* __restrict__ Abf) {
    size_t i = ((size_t)blockIdx.x * 256 + threadIdx.x) * 8;
    float4 f0 = *reinterpret_cast<const float4*>(A + i);
    float4 f1 = *reinterpret_cast<const float4*>(A + i + 4);
    union { short8 s8; __hip_bfloat16 h[8]; } u;
    u.h[0] = __float2bfloat16(f0.x);
    u.h[1] = __float2bfloat16(f0.y);
    u.h[2] = __float2bfloat16(f0.z);
    u.h[3] = __float2bfloat16(f0.w);
    u.h[4] = __float2bfloat16(f1.x);
    u.h[5] = __float2bfloat16(f1.y);
    u.h[6] = __float2bfloat16(f1.z);
    u.h[7] = __float2bfloat16(f1.w);
    *reinterpret_cast<short8*>(&Abf[i]) = u.s8;
}

// ------- scale+transpose: Bt[n,e] = W[e] * B[e,n], fp32 -> bf16 ---------
__global__ __launch_bounds__(256) void cvtB(const float* __restrict__ B,
                                            const float* __restrict__ W,
                                            __hip_bfloat16* __restrict__ Bt) {
    __shared__ float tile[32][33];
    const int tx = threadIdx.x & 31;
    const int ty = threadIdx.x >> 5;
    const int n0 = blockIdx.x * 32;
    const int e0 = blockIdx.y * 32;
#pragma unroll
    for (int r = 0; r < 4; ++r) {
        int e = e0 + ty + r * 8;
        tile[ty + r * 8][tx] = B[(size_t)e * N_DIM + n0 + tx] * W[e];
    }
    __syncthreads();
#pragma unroll
    for (int r = 0; r < 4; ++r) {
        int n = n0 + ty + r * 8;
        Bt[(size_t)n * E_DIM + e0 + tx] = __float2bfloat16(tile[tx][ty + r * 8]);
    }
}

// ---------------- GEMM: C[N,N] = Abf[N,E] * Btbf[N,E]^T ----------------
// LDS-traffic-reduced: A staged via LDS (2x32 KiB dbuf, 8-slot XOR swizzle);
// B fragments load GLOBAL->REGISTER (reg double-buffer, one K-tile ahead).
// LDS/K-tile: 160 KB (was 256 KB) -> MFMA pipe becomes critical. One
// barrier + exact vmcnt(0) per K-tile. XCD owns 4 tile-columns (B slice
// 4 MB = L2-resident).

template<bool STG>
__device__ __forceinline__ void ktile(
    const char* Acur, char* Anxt,
    bf16x8 (&bfC)[4][2], bf16x8 (&bfN)[4][2],
    const char*& aP, const char* (&bP)[4],
    int tid, int wm, int fr, int kq,
    f32x4 (&acc)[8][4])
{
    asm volatile("s_waitcnt vmcnt(0)" ::: "memory");   // A-DMA(kt) + B-regs(kt) done
    __builtin_amdgcn_s_barrier();                      // publish A(kt); old-buf reads retired
    __builtin_amdgcn_sched_barrier(0);

    if (STG) {   // issue next tile's B-frag loads (regs) + A DMA (LDS)
#pragma unroll
        for (int ni = 0; ni < 4; ++ni)
#pragma unroll
            for (int h = 0; h < 2; ++h)
                bfN[ni][h] = *reinterpret_cast<const bf16x8*>(bP[ni] + 128 + h * 64);
#pragma unroll
        for (int q = 0; q < 4; ++q)
            GLD(aP + (size_t)q * 262144, Anxt + q * 8192 + tid * 16);
#pragma unroll
        for (int ni = 0; ni < 4; ++ni) bP[ni] += 128;
        aP += 128;
    }
    __builtin_amdgcn_sched_barrier(0);

    bf16x8 af[4][2];
    // ---- cluster 0: m 0..3 ----
#pragma unroll
    for (int m = 0; m < 4; ++m)
#pragma unroll
        for (int h = 0; h < 2; ++h)
            af[m][h] = *reinterpret_cast<const bf16x8*>(
                Acur + (wm * 128 + m * 16 + fr) * 128 + ((((h << 2) | kq) ^ (fr & 7)) * 16));
    __builtin_amdgcn_sched_barrier(0);
    asm volatile("s_waitcnt lgkmcnt(0)" ::: "memory");
    __builtin_amdgcn_sched_barrier(0);
    __builtin_amdgcn_s_setprio(1);
#pragma unroll
    for (int m = 0; m < 4; ++m)
#pragma unroll
        for (int n = 0; n < 4; ++n)
#pragma unroll
            for (int h = 0; h < 2; ++h)
                acc[m][n] = __builtin_amdgcn_mfma_f32_16x16x32_bf16(
                    af[m][h], bfC[n][h], acc[m][n], 0, 0, 0);
    __builtin_amdgcn_s_setprio(0);
    __builtin_amdgcn_sched_barrier(0);

    // ---- cluster 1: m 4..7 (af registers reused) ----
#pragma unroll
    for (int m = 0; m < 4; ++m)
#pragma unroll
        for (int h = 0; h < 2; ++h)
            af[m][h] = *reinterpret_cast<const bf16x8*>(
                Acur + (wm * 128 + (m + 4) * 16 + fr) * 128 + ((((h << 2) | kq) ^ (fr & 7)) * 16));
    __builtin_amdgcn_sched_barrier(0);
    asm volatile("s_waitcnt lgkmcnt(0)" ::: "memory");
    __builtin_amdgcn_sched_barrier(0);
    __builtin_amdgcn_s_setprio(1);
#pragma unroll
    for (int m = 0; m < 4; ++m)
#pragma unroll
        for (int n = 0; n < 4; ++n)
#pragma unroll
            for (int h = 0; h < 2; ++h)
                acc[4 + m][n] = __builtin_amdgcn_mfma_f32_16x16x32_bf16(
                    af[m][h], bfC[n][h], acc[4 + m][n], 0, 0, 0);
    __builtin_amdgcn_s_setprio(0);
}

__global__ __launch_bounds__(512, 2) void gemm_bt(const __hip_bfloat16* __restrict__ A,
                                                  const __hip_bfloat16* __restrict__ B,
                                                  float* __restrict__ C) {
    __shared__ __align__(16) char lds[65536];   // A only: 2 buffers x 32 KiB

    const int tid  = threadIdx.x;
    const int lane = tid & 63;
    const int wave = tid >> 6;
    const int wm = wave >> 2;          // 0..1
    const int wn = wave & 3;           // 0..3
    const int fr = lane & 15;
    const int kq = lane >> 4;          // 0..3

    // mapping: XCD owns 4 tile-columns (B slice 4 MB = L2-resident);
    // tm sweeps within XCD. bid = tm*32 + sub*8 + xcd (bijective).
    const int bid = blockIdx.x;
    const int xcd = bid & 7;
    const int sub = (bid >> 3) & 3;
    const int tm  = bid >> 5;          // 0..31
    const int tn  = xcd * 4 + sub;     // 0..31

    // A staging source (pre-swizzled k-slot, rule 21)
    const char* aP = (const char*)A +
        (((size_t)tm * 256 + (tid >> 3)) * E_DIM + ((tid & 7) ^ ((tid >> 3) & 7)) * 8) * 2;

    // B fragment pointers (per lane; k-offset advances 128 B per K-tile)
    const char* bP[4];
#pragma unroll
    for (int ni = 0; ni < 4; ++ni)
        bP[ni] = (const char*)B +
            (((size_t)tn * 256 + wn * 64 + ni * 16 + fr) * E_DIM + kq * 8) * 2;

    // prologue: B(0) -> regs, A(0) -> LDS buf0
    bf16x8 bfA[4][2], bfB[4][2];
#pragma unroll
    for (int ni = 0; ni < 4; ++ni)
#pragma unroll
        for (int h = 0; h < 2; ++h)
            bfA[ni][h] = *reinterpret_cast<const bf16x8*>(bP[ni] + h * 64);
#pragma unroll
    for (int q = 0; q < 4; ++q)
        GLD(aP + (size_t)q * 262144, lds + q * 8192 + tid * 16);
    aP += 128;   // FIX (R10 bug): advance to K-tile 1 so STG stages kt+1, not kt

    f32x4 acc[8][4] = {};

    for (int it = 0; it < NKT / 2 - 1; ++it) {
        ktile<true>(lds,         lds + 32768, bfA, bfB, aP, bP, tid, wm, fr, kq, acc);
        ktile<true>(lds + 32768, lds,         bfB, bfA, aP, bP, tid, wm, fr, kq, acc);
    }
    ktile<true >(lds,         lds + 32768, bfA, bfB, aP, bP, tid, wm, fr, kq, acc);
    ktile<false>(lds + 32768, lds,         bfB, bfA, aP, bP, tid, wm, fr, kq, acc);

    // ---- epilogue: per 64-row band, transpose through LDS, then stream out
    // full-line nontemporal f32x4 stores (verified R6 structure).
    float* bandbuf = (float*)lds;      // 64 KiB = 64 rows x 256 cols x 4B
    const int q4 = (lane >> 4) * 4;
#pragma unroll
    for (int b = 0; b < 4; ++b) {
        __syncthreads();               // K-loop reads / previous band stores done
        if (wm == (b >> 1)) {
            const int mi0 = (b & 1) * 4;
#pragma unroll
            for (int m = 0; m < 4; ++m)
#pragma unroll
                for (int ni = 0; ni < 4; ++ni)
#pragma unroll
                    for (int j = 0; j < 4; ++j)
                        bandbuf[(m * 16 + q4 + j) * 256 + wn * 64 + ni * 16 + fr] =
                            acc[mi0 + m][ni][j];
        }
        __syncthreads();
        const int rbase = tid >> 6;        // 0..7
        const int c4 = (tid & 63) * 4;     // col in floats
#pragma unroll
        for (int r8 = 0; r8 < 8; ++r8) {
            const int row = r8 * 8 + rbase;
            f32x4 v = *reinterpret_cast<const f32x4*>(&bandbuf[row * 256 + c4]);
            __builtin_nontemporal_store(v, reinterpret_cast<f32x4*>(
                &C[(size_t)(tm * 256 + b * 64 + row) * N_DIM + tn * 256 + c4]));
        }
    }
}

extern "C" void kernel_launch(void* const* d_in, const int* in_sizes, int n_in,
                              void* d_out, int out_size, void* d_ws, size_t ws_size,
                              hipStream_t stream) {
    const float* A = (const float*)d_in[0];   // DV2_H        [N, E]
    const float* B = (const float*)d_in[1];   // invDE_HT_DV2 [E, N]
    const float* W = (const float*)d_in[2];   // W            [E]
    float* C = (float*)d_out;                 // G            [N, N] fp32

    __hip_bfloat16* Abf  = (__hip_bfloat16*)d_ws;               // 32 MB
    __hip_bfloat16* Btbf = Abf + (size_t)N_DIM * E_DIM;         // 32 MB

    cvtA<<<(N_DIM * (size_t)E_DIM) / 8 / 256, 256, 0, stream>>>(A, Abf);
    dim3 tgrid(N_DIM / 32, E_DIM / 32);
    cvtB<<<tgrid, 256, 0, stream>>>(B, W, Btbf);
    gemm_bt<<<(N_DIM / 256) * (N_DIM / 256), 512, 0, stream>>>(Abf, Btbf, C);
}

// Round 12
// 278.836 us; speedup vs baseline: 1.4872x; 1.4872x over previous
//
#include <hip/hip_runtime.h>
#include <hip/hip_bf16.h>

#define N_DIM 8192
#define E_DIM 2048
#define NKT 32           // K tiles of BK=64

typedef __bf16 bf16x8 __attribute__((ext_vector_type(8)));
typedef float  f32x4  __attribute__((ext_vector_type(4)));
typedef short  short8 __attribute__((ext_vector_type(8)));

#define GLD(gp, lp) __builtin_amdgcn_global_load_lds( \
    (const __attribute__((address_space(1))) void*)(gp), \
    (__attribute__((address_space(3))) void*)(lp), 16, 0, 0)

// ---------------- conversion: A fp32 [N,E] -> bf16 [N,E] ----------------
__global__ __launch_bounds__(256) void cvtA(const float* __restrict__ A,
                                            __hip_bfloat16* __restrict__ Abf) {
    size_t i = ((size_t)blockIdx.x * 256 + threadIdx.x) * 8;
    float4 f0 = *reinterpret_cast<const float4*>(A + i);
    float4 f1 = *reinterpret_cast<const float4*>(A + i + 4);
    union { short8 s8; __hip_bfloat16 h[8]; } u;
    u.h[0] = __float2bfloat16(f0.x);
    u.h[1] = __float2bfloat16(f0.y);
    u.h[2] = __float2bfloat16(f0.z);
    u.h[3] = __float2bfloat16(f0.w);
    u.h[4] = __float2bfloat16(f1.x);
    u.h[5] = __float2bfloat16(f1.y);
    u.h[6] = __float2bfloat16(f1.z);
    u.h[7] = __float2bfloat16(f1.w);
    *reinterpret_cast<short8*>(&Abf[i]) = u.s8;
}

// ------- scale+transpose: Bt[n,e] = W[e] * B[e,n], fp32 -> bf16 ---------
__global__ __launch_bounds__(256) void cvtB(const float* __restrict__ B,
                                            const float* __restrict__ W,
                                            __hip_bfloat16* __restrict__ Bt) {
    __shared__ float tile[32][33];
    const int tx = threadIdx.x & 31;
    const int ty = threadIdx.x >> 5;
    const int n0 = blockIdx.x * 32;
    const int e0 = blockIdx.y * 32;
#pragma unroll
    for (int r = 0; r < 4; ++r) {
        int e = e0 + ty + r * 8;
        tile[ty + r * 8][tx] = B[(size_t)e * N_DIM + n0 + tx] * W[e];
    }
    __syncthreads();
#pragma unroll
    for (int r = 0; r < 4; ++r) {
        int n = n0 + ty + r * 8;
        Bt[(size_t)n * E_DIM + e0 + tx] = __float2bfloat16(tile[tx][ty + r * 8]);
    }
}

// ---------------- GEMM: C[N,N] = Abf[N,E] * Btbf[N,E]^T ----------------
// R8 structure (best verified: 256x256, BK=64, 8 waves, 2 LDS buffers,
// 4 fine phases per K-tile, 8-slot XOR swizzle) with R11's XCD-column
// mapping: each XCD owns 4 tile-columns -> B slice (4 MB) is L2-resident,
// A panels come from L3. Cuts the per-tile vmcnt(0) drain latency.

template<bool RDA, bool RDB, int MH, int NP, bool STGA, bool STGB, bool VMD>
__device__ __forceinline__ void phase(
    const char* Acur, const char* Bcur,
    char* Anxt, char* Bnxt,
    const char* aP, const char* bP,
    int tid, int wm, int wn, int fr, int kq,
    bf16x8 (&af)[4][2], bf16x8 (&bf)[4][2], f32x4 (&acc)[8][4])
{
    if (RDA) {
#pragma unroll
        for (int f = 0; f < 4; ++f)
#pragma unroll
            for (int h = 0; h < 2; ++h) {
                const int row = wm * 128 + (MH * 4 + f) * 16 + fr;
                af[f][h] = *reinterpret_cast<const bf16x8*>(
                    Acur + row * 128 + ((((h << 2) | kq) ^ (fr & 7)) * 16));
            }
    }
    if (RDB) {
#pragma unroll
        for (int n = 0; n < 2; ++n)
#pragma unroll
            for (int h = 0; h < 2; ++h) {
                const int row = wn * 64 + (NP * 2 + n) * 16 + fr;
                bf[NP * 2 + n][h] = *reinterpret_cast<const bf16x8*>(
                    Bcur + row * 128 + ((((h << 2) | kq) ^ (fr & 7)) * 16));
            }
    }
    if (STGA) {
#pragma unroll
        for (int q = 0; q < 4; ++q)
            GLD(aP + (size_t)q * 262144, Anxt + q * 8192 + tid * 16);
    }
    if (STGB) {
#pragma unroll
        for (int q = 0; q < 4; ++q)
            GLD(bP + (size_t)q * 262144, Bnxt + q * 8192 + tid * 16);
    }
    __builtin_amdgcn_sched_barrier(0);
    __builtin_amdgcn_s_barrier();
    asm volatile("s_waitcnt lgkmcnt(0)" ::: "memory");
    __builtin_amdgcn_sched_barrier(0);
    __builtin_amdgcn_s_setprio(1);
#pragma unroll
    for (int f = 0; f < 4; ++f)
#pragma unroll
        for (int n = 0; n < 2; ++n)
#pragma unroll
            for (int h = 0; h < 2; ++h)
                acc[MH * 4 + f][NP * 2 + n] = __builtin_amdgcn_mfma_f32_16x16x32_bf16(
                    af[f][h], bf[NP * 2 + n][h], acc[MH * 4 + f][NP * 2 + n], 0, 0, 0);
    __builtin_amdgcn_s_setprio(0);
    __builtin_amdgcn_sched_barrier(0);
    if (VMD) asm volatile("s_waitcnt vmcnt(0)" ::: "memory");
    __builtin_amdgcn_s_barrier();
}

template<bool STG>
__device__ __forceinline__ void ktile(
    const char* Acur, const char* Bcur, char* Anxt, char* Bnxt,
    const char*& aP, const char*& bP,
    int tid, int wm, int wn, int fr, int kq,
    bf16x8 (&af)[4][2], bf16x8 (&bf)[4][2], f32x4 (&acc)[8][4])
{
    phase<true,  true,  0, 0, STG,  false, false>(Acur, Bcur, Anxt, Bnxt, aP, bP,
        tid, wm, wn, fr, kq, af, bf, acc);
    phase<false, true,  0, 1, false, STG,  false>(Acur, Bcur, Anxt, Bnxt, aP, bP,
        tid, wm, wn, fr, kq, af, bf, acc);
    if (STG) { aP += 128; bP += 128; }
    phase<true,  false, 1, 0, false, false, false>(Acur, Bcur, Anxt, Bnxt, aP, bP,
        tid, wm, wn, fr, kq, af, bf, acc);
    phase<false, false, 1, 1, false, false, true >(Acur, Bcur, Anxt, Bnxt, aP, bP,
        tid, wm, wn, fr, kq, af, bf, acc);
}

__global__ __launch_bounds__(512, 2) void gemm_bt(const __hip_bfloat16* __restrict__ A,
                                                  const __hip_bfloat16* __restrict__ B,
                                                  float* __restrict__ C) {
    __shared__ __align__(16) char lds[131072];
    char* ldsA = (char*)lds;            // 2 buffers x 32 KiB (256 rows x 128 B)
    char* ldsB = (char*)lds + 65536;    // 2 buffers x 32 KiB

    const int tid  = threadIdx.x;
    const int lane = tid & 63;
    const int wave = tid >> 6;
    const int wm = wave >> 2;          // 0..1
    const int wn = wave & 3;           // 0..3
    const int fr = lane & 15;
    const int kq = lane >> 4;          // 0..3

    // XCD-column mapping (R11, FETCH-verified): XCD owns 4 tile-columns
    // (B slice 4 MB = L2-resident); tm sweeps. bid = tm*32 + sub*8 + xcd.
    const int bid = blockIdx.x;
    const int xcd = bid & 7;
    const int sub = (bid >> 3) & 3;
    const int tm  = bid >> 5;          // 0..31
    const int tn  = xcd * 4 + sub;     // 0..31

    // staging source pointers (pre-swizzled k-slot, rule 21)
    const char* aP = (const char*)A +
        (((size_t)tm * 256 + (tid >> 3)) * E_DIM + ((tid & 7) ^ ((tid >> 3) & 7)) * 8) * 2;
    const char* bP = (const char*)B +
        (((size_t)tn * 256 + (tid >> 3)) * E_DIM + ((tid & 7) ^ ((tid >> 3) & 7)) * 8) * 2;

    // prologue: stage tile 0 into buffer 0
#pragma unroll
    for (int q = 0; q < 4; ++q) {
        GLD(aP + (size_t)q * 262144, ldsA + q * 8192 + tid * 16);
        GLD(bP + (size_t)q * 262144, ldsB + q * 8192 + tid * 16);
    }
    aP += 128; bP += 128;
    asm volatile("s_waitcnt vmcnt(0)" ::: "memory");
    __builtin_amdgcn_s_barrier();

    f32x4 acc[8][4] = {};
    bf16x8 af[4][2], bf[4][2];

    for (int it = 0; it < NKT / 2 - 1; ++it) {
        ktile<true>(ldsA,         ldsB,         ldsA + 32768, ldsB + 32768,
                    aP, bP, tid, wm, wn, fr, kq, af, bf, acc);
        ktile<true>(ldsA + 32768, ldsB + 32768, ldsA,         ldsB,
                    aP, bP, tid, wm, wn, fr, kq, af, bf, acc);
    }
    ktile<true >(ldsA,         ldsB,         ldsA + 32768, ldsB + 32768,
                 aP, bP, tid, wm, wn, fr, kq, af, bf, acc);
    ktile<false>(ldsA + 32768, ldsB + 32768, ldsA,         ldsB,
                 aP, bP, tid, wm, wn, fr, kq, af, bf, acc);

    // ---- epilogue: per 64-row band, transpose through LDS, then stream out
    // full-line nontemporal f32x4 stores (64 threads x 16B = 1 KiB per row).
    float* bandbuf = (float*)lds;      // 64 KiB = 64 rows x 256 cols x 4B
    const int q4 = (lane >> 4) * 4;
#pragma unroll
    for (int b = 0; b < 4; ++b) {
        __syncthreads();               // K-loop reads / previous band stores done
        if (wm == (b >> 1)) {
            const int mi0 = (b & 1) * 4;
#pragma unroll
            for (int m = 0; m < 4; ++m)
#pragma unroll
                for (int ni = 0; ni < 4; ++ni)
#pragma unroll
                    for (int j = 0; j < 4; ++j)
                        bandbuf[(m * 16 + q4 + j) * 256 + wn * 64 + ni * 16 + fr] =
                            acc[mi0 + m][ni][j];
        }
        __syncthreads();
        const int rbase = tid >> 6;        // 0..7
        const int c4 = (tid & 63) * 4;     // col in floats
#pragma unroll
        for (int r8 = 0; r8 < 8; ++r8) {
            const int row = r8 * 8 + rbase;
            f32x4 v = *reinterpret_cast<const f32x4*>(&bandbuf[row * 256 + c4]);
            __builtin_nontemporal_store(v, reinterpret_cast<f32x4*>(
                &C[(size_t)(tm * 256 + b * 64 + row) * N_DIM + tn * 256 + c4]));
        }
    }
}

extern "C" void kernel_launch(void* const* d_in, const int* in_sizes, int n_in,
                              void* d_out, int out_size, void* d_ws, size_t ws_size,
                              hipStream_t stream) {
    const float* A = (const float*)d_in[0];   // DV2_H        [N, E]
    const float* B = (const float*)d_in[1];   // invDE_HT_DV2 [E, N]
    const float* W = (const float*)d_in[2];   // W            [E]
    float* C = (float*)d_out;                 // G            [N, N] fp32

    __hip_bfloat16* Abf  = (__hip_bfloat16*)d_ws;               // 32 MB
    __hip_bfloat16* Btbf = Abf + (size_t)N_DIM * E_DIM;         // 32 MB

    cvtA<<<(N_DIM * (size_t)E_DIM) / 8 / 256, 256, 0, stream>>>(A, Abf);
    dim3 tgrid(N_DIM / 32, E_DIM / 32);
    cvtB<<<tgrid, 256, 0, stream>>>(B, W, Btbf);
    gemm_bt<<<(N_DIM / 256) * (N_DIM / 256), 512, 0, stream>>>(Abf, Btbf, C);
}